// Round 12
// baseline (279.942 us; speedup 1.0000x reference)
//
#include <hip/hip_runtime.h>
#include <hip/hip_bf16.h>
#include <hip/hip_cooperative_groups.h>

namespace cg = cooperative_groups;

// Problem: x(4,256,64,64), offset(4,18,64,64), mask(4,9,64,64),
// weight(256,256,3,3) -> out(4,256,64,64). stride=1, pad=1, K=3.
// R12: ONE cooperative kernel: prep (transpose x -> bf16 BHWC | weight ->
// B'[ob][kc][row]) -> grid.sync -> R10-style fused sample+GEMM with
// lane-parallel sampling setup: lane (i,c) computes row i / corner c's
// address+weight once, readlane-broadcast to SGPRs (kills the 64x-redundant
// wave-uniform VALU setup that made VALUBusy 36%).
#define BN 4
#define CN 256
#define HN 64
#define WN 64
#define ON 256
#define KKN 9
#define HWN 4096
#define KDIM 2304
#define KC 288

using frag_ab = __attribute__((ext_vector_type(8))) short;
using frag_cd = __attribute__((ext_vector_type(4))) float;
using short4v = __attribute__((ext_vector_type(4))) short;
using f32x2   = __attribute__((ext_vector_type(2))) float;

static __device__ inline short f2bf(float f) {
    union { float f; unsigned u; } v; v.f = f;
    unsigned r = v.u + 0x7fffu + ((v.u >> 16) & 1u);
    return (short)(r >> 16);
}
static __device__ inline f32x2 unpk(unsigned u) {
    union { unsigned v; float f; } a, b;
    a.v = u << 16;
    b.v = u & 0xffff0000u;
    f32x2 r; r[0] = a.f; r[1] = b.f; return r;
}
static __device__ inline float rlane_f(float v, int l) {
    union { float f; int i; } u; u.f = v;
    u.i = __builtin_amdgcn_readlane(u.i, l);
    return u.f;
}

__global__ __launch_bounds__(256, 2) void mono_kernel(const float* __restrict__ x,
                                                      const float* __restrict__ wsrc,
                                                      const float* __restrict__ offs,
                                                      const float* __restrict__ maskp,
                                                      short* __restrict__ xb16,
                                                      short* __restrict__ wtb,
                                                      float* __restrict__ out) {
    __shared__ union {
        float tile[64][65];       // phase 1 transpose
        short Ab[2][8448];        // phase 2: 2 x A-tile (stride-33 chunks)
        float outb[32 * 257];     // epilogue
    } sm;
    int tid = threadIdx.x;
    int bid = blockIdx.x;

    // ================= phase 1a: x BCHW fp32 -> BHWC bf16 (2 tiles) ======
    #pragma unroll 1
    for (int t = 0; t < 2; ++t) {
        int bidx = bid * 2 + t;
        int b   = bidx >> 8;
        int rem = bidx & 255;
        int c0  = (rem >> 6) * 64;
        int p0  = (rem & 63) * 64;
        int tp = tid & 63, tc = tid >> 6;
        __syncthreads();
        for (int i = 0; i < 16; ++i) {
            int c = tc + i * 4;
            sm.tile[c][tp] = x[(b * CN + c0 + c) * HWN + p0 + tp];
        }
        __syncthreads();
        int tcc = tid & 63, tpp = tid >> 6;
        for (int i = 0; i < 16; ++i) {
            int p = tpp + i * 4;
            xb16[(b * HWN + p0 + p) * CN + c0 + tcc] = f2bf(sm.tile[tcc][p]);
        }
    }
    // ================= phase 1b: weight repack (144 chunks/block) ========
    if (tid < 144) {
        int chunk = bid * 144 + tid;          // < 512*144 = 73728
        int ob  = chunk / (KC * 64);
        int rem = chunk - ob * (KC * 64);
        int kc  = rem >> 6;
        int row = rem & 63;
        int o   = ob * 64 + row;
        int kk  = kc >> 5;
        int oct = kc & 31;
        frag_ab v;
        #pragma unroll
        for (int e = 0; e < 8; ++e)
            v[e] = f2bf(wsrc[(o * CN + oct * 8 + e) * 9 + kk]);
        *(frag_ab*)&wtb[(size_t)chunk * 8] = v;
    }
    __threadfence();
    cg::this_grid().sync();

    // ================= phase 2: fused sample + GEMM ======================
    int m0  = bid * 32;
    int b   = m0 >> 12;
    int h   = (m0 >> 6) & 63;
    int w0  = m0 & 63;
    int wv  = tid >> 6, lane = tid & 63;
    int q   = lane >> 4, r = lane & 15;
    int wrow0 = w0 + wv * 8;
    int wbase = 33 * (lane >> 1) * 8 + (lane & 1) * 4;
    // lane-parallel setup roles (lanes 32-63 duplicate 0-31; readlane uses 0-31)
    int i_  = (lane >> 2) & 7;
    int cy_ = (lane >> 1) & 1;
    int cx_ = lane & 1;
    int wc_ = wrow0 + i_;

    frag_cd acc[2][4];
    #pragma unroll
    for (int i = 0; i < 2; ++i)
        #pragma unroll
        for (int j = 0; j < 4; ++j)
            acc[i][j] = (frag_cd){0.f, 0.f, 0.f, 0.f};

    #pragma unroll 1
    for (int kk = 0; kk < KKN; ++kk) {
        short* dst = sm.Ab[kk & 1];
        int ki = kk / 3, kj = kk - ki * 3;
        // ---- lane-parallel setup: this lane's (row i_, corner (cy_,cx_)) ----
        float dy = offs[((b * 18 + kk * 2) * 64 + h) * 64 + wc_];
        float dx = offs[((b * 18 + kk * 2 + 1) * 64 + h) * 64 + wc_];
        float mv = maskp[((b * 9 + kk) * 64 + h) * 64 + wc_];
        float py = (float)(h - 1 + ki) + dy;
        float px = (float)(wc_ - 1 + kj) + dx;
        float y0f = floorf(py), x0f = floorf(px);
        float wy = py - y0f, wx = px - x0f;
        int yy = (int)y0f + cy_;
        int xx = (int)x0f + cx_;
        bool valid = (yy >= 0 && yy < HN && xx >= 0 && xx < WN);
        int yc = min(max(yy, 0), HN - 1);
        int xc = min(max(xx, 0), WN - 1);
        int addr = ((b * HN + yc) * WN + xc) * CN;
        float wgt = (cy_ ? wy : 1.f - wy) * (cx_ ? wx : 1.f - wx) * mv;
        wgt = valid ? wgt : 0.f;
        // ---- per row: broadcast 4 addr+wgt, gather coalesced, combine ----
        #pragma unroll
        for (int i = 0; i < 8; ++i) {
            int   a0 = __builtin_amdgcn_readlane(addr, i * 4 + 0);
            int   a1 = __builtin_amdgcn_readlane(addr, i * 4 + 1);
            int   a2 = __builtin_amdgcn_readlane(addr, i * 4 + 2);
            int   a3 = __builtin_amdgcn_readlane(addr, i * 4 + 3);
            float w0s = rlane_f(wgt, i * 4 + 0);
            float w1s = rlane_f(wgt, i * 4 + 1);
            float w2s = rlane_f(wgt, i * 4 + 2);
            float w3s = rlane_f(wgt, i * 4 + 3);
            short4v v0 = *(const short4v*)&xb16[a0 + lane * 4];
            short4v v1 = *(const short4v*)&xb16[a1 + lane * 4];
            short4v v2 = *(const short4v*)&xb16[a2 + lane * 4];
            short4v v3 = *(const short4v*)&xb16[a3 + lane * 4];
            union { short4v s; unsigned u[2]; } u0, u1, u2, u3;
            u0.s = v0; u1.s = v1; u2.s = v2; u3.s = v3;
            short4v res;
            #pragma unroll
            for (int p = 0; p < 2; ++p) {
                f32x2 s2 = unpk(u0.u[p]) * w0s;
                s2 += unpk(u1.u[p]) * w1s;
                s2 += unpk(u2.u[p]) * w2s;
                s2 += unpk(u3.u[p]) * w3s;
                __hip_bfloat162 p2 =
                    __float22bfloat162_rn(make_float2(s2[0], s2[1]));
                res[2 * p]     = *(short*)&p2.x;
                res[2 * p + 1] = *(short*)&p2.y;
            }
            *(short4v*)&dst[wbase + (wv * 8 + i) * 8] = res;
        }
        __syncthreads();
        // ---- MFMA phase: 8 k16-steps; A from LDS, B direct global (L2) ----
        #pragma unroll
        for (int ks = 0; ks < 8; ++ks) {
            frag_ab af[2], bf[4];
            #pragma unroll
            for (int i = 0; i < 2; ++i)
                af[i] = *(const frag_ab*)
                    &dst[(33 * (ks * 4 + q) + i * 16 + r) * 8];
            #pragma unroll
            for (int j = 0; j < 4; ++j)
                bf[j] = *(const frag_ab*)
                    &wtb[(((size_t)wv * KC + kk * 32 + ks * 4 + q) * 64
                          + j * 16 + r) * 8];
            #pragma unroll
            for (int i = 0; i < 2; ++i)
                #pragma unroll
                for (int j = 0; j < 4; ++j)
                    acc[i][j] = __builtin_amdgcn_mfma_f32_16x16x32_bf16(
                        af[i], bf[j], acc[i][j], 0, 0, 0);
        }
        // dbuf: buffer protected by next iteration's post-sample barrier
    }
    __syncthreads();

    // ---- epilogue: acc (row=i*16+q*4+reg, col=wv*64+j*16+r) -> LDS -> BOHW
    #pragma unroll
    for (int i = 0; i < 2; ++i)
        #pragma unroll
        for (int j = 0; j < 4; ++j) {
            int ml = i * 16 + q * 4;
            int ol = wv * 64 + j * 16 + r;
            sm.outb[(ml + 0) * 257 + ol] = acc[i][j][0];
            sm.outb[(ml + 1) * 257 + ol] = acc[i][j][1];
            sm.outb[(ml + 2) * 257 + ol] = acc[i][j][2];
            sm.outb[(ml + 3) * 257 + ol] = acc[i][j][3];
        }
    __syncthreads();
    {
        int ww = tid & 31;
        int og = tid >> 5;
        #pragma unroll
        for (int oo = 0; oo < 32; ++oo) {
            int o = oo * 8 + og;
            out[(((size_t)b * ON + o) * HN + h) * WN + w0 + ww] =
                sm.outb[ww * 257 + o];
        }
    }
}

extern "C" void kernel_launch(void* const* d_in, const int* in_sizes, int n_in,
                              void* d_out, int out_size, void* d_ws, size_t ws_size,
                              hipStream_t stream) {
    const float* x      = (const float*)d_in[0];
    const float* offset = (const float*)d_in[1];
    const float* mask   = (const float*)d_in[2];
    const float* weight = (const float*)d_in[3];
    float* out = (float*)d_out;

    short* xb16 = (short*)d_ws;
    short* wtb  = (short*)((char*)d_ws + 8388608);

    void* args[] = { (void*)&x, (void*)&weight, (void*)&offset, (void*)&mask,
                     (void*)&xb16, (void*)&wtb, (void*)&out };
    hipLaunchCooperativeKernel((const void*)mono_kernel, dim3(512), dim3(256),
                               args, 0, stream);
}